// Round 21
// baseline (234.847 us; speedup 1.0000x reference)
//
#include <hip/hip_runtime.h>

// ---------------------------------------------------------------------------
// GATBottleneck (ALL I/O fp32; compute bf16 MFMA, fp32 accum)
//
//  1. wgatp: WgT2p bf16 [4096][512]; WgT2p[j*8+h][k] = w_gat[k][h*512+j]
//  2. cvt2 : w_reduce + w_restore fp32 -> bf16 (single launch)
//  3. gemm_redf: xr = relu(bn(x_nchw @ w_reduce^T))  [16384][512] bf16
//              NOW double-buffered (24KB LDS, ONE barrier/K-tile) at
//              4 blocks/CU (R19 recipe applied)
//  4. attproj/att: alpha logits via factored projections       (fp32)
//  5. alphapre: per-(node,head) 5-edge softmax -> alf_g bf16 [16384][40]
//  6. gemmf2 : FUSED Y-projection + GAT stencil, 256x128, 2 blocks/CU
//  7. gemm_res3: out = relu(bn(gat @ w_restore^T) + x) -> fp32 NCHW
// edge_index is the fixed 4-neighbor grid + self loops -> analytic.
// ---------------------------------------------------------------------------

typedef unsigned short u16;
typedef __attribute__((ext_vector_type(4))) unsigned short u16x4;
typedef __attribute__((ext_vector_type(8))) unsigned short u16x8;
typedef __attribute__((ext_vector_type(8))) __bf16 bf16x8;
typedef __attribute__((ext_vector_type(2))) __bf16 bf16x2;
typedef __attribute__((ext_vector_type(4))) float f32x4;

#if defined(__has_builtin)
#if __has_builtin(__builtin_amdgcn_fdot2_f32_bf16)
#define HAVE_DOT2 1
#endif
#endif

#define B_    64
#define CIN   1024
#define CRED  512
#define COUT  1024
#define NPIX  256
#define HEADS 8
#define KGAT  4096
#define MTOT  16384
#define EPSB  1e-5f

__device__ __forceinline__ float b2f(u16 u) {
  union { unsigned u; float f; } c; c.u = ((unsigned)u) << 16; return c.f;
}
__device__ __forceinline__ u16 f2b(float f) {
  union { float f; unsigned u; } c; c.f = f;
  unsigned r = (c.u + 0x7FFFu + ((c.u >> 16) & 1u)) >> 16;
  return (u16)r;
}

__device__ __forceinline__ void gload_lds16(const void* g, void* lds) {
  __builtin_amdgcn_global_load_lds(
      (const __attribute__((address_space(1))) void*)g,
      (__attribute__((address_space(3))) void*)lds, 16, 0, 0);
}

union U8u {
  u16x8 v;
  bf16x2 p[4];
};

// ---- alphapre: alf_g[n][e*8+h] = softmax-alpha (1/8 folded), bf16 ---------
__global__ __launch_bounds__(256) void alphapre_kernel(
    const float* __restrict__ a_all, u16* __restrict__ alf_g)
{
  const int nh = blockIdx.x * 256 + threadIdx.x;   // 0..131071
  const int ng = nh >> 3, h = nh & 7;              // global node, head
  const int n = ng & 255;
  const size_t nbase = (size_t)(ng >> 8) * NPIX;
  const int gi = n >> 4, gj = n & 15;
  int vv[5];
  vv[0] = n;
  vv[1] = (gi > 0)  ? n - 16 : -1;
  vv[2] = (gi < 15) ? n + 16 : -1;
  vv[3] = (gj > 0)  ? n - 1  : -1;
  vv[4] = (gj < 15) ? n + 1  : -1;
  const float* a_src = a_all;
  const float* a_dst = a_all + (size_t)MTOT * HEADS;
  const float ad = a_dst[(nbase + n) * HEADS + h];
  float l[5]; float mx = -1e30f;
#pragma unroll
  for (int e = 0; e < 5; ++e) {
    if (vv[e] >= 0) {
      const float xx = a_src[(nbase + vv[e]) * HEADS + h] + ad;
      l[e] = xx > 0.f ? xx : 0.2f * xx;            // leaky_relu(0.2)
      mx = fmaxf(mx, l[e]);
    } else l[e] = -1e30f;
  }
  float s = 0.f, ee[5];
#pragma unroll
  for (int e = 0; e < 5; ++e) {
    ee[e] = (vv[e] >= 0) ? __expf(l[e] - mx) : 0.f;
    s += ee[e];
  }
  const float inv = 0.125f / s;                    // head-mean folded
#pragma unroll
  for (int e = 0; e < 5; ++e)
    alf_g[(size_t)ng * 40 + e * 8 + h] = f2b(ee[e] * inv);
}

// ===== FUSED 256x128 GEMM + GAT stencil, 2 blocks/CU (R19-verified) ========
__global__ __launch_bounds__(512, 4) void gemmf2_kernel(
    const u16* __restrict__ A, const u16* __restrict__ Btp,
    const u16* __restrict__ alf_g, const float* __restrict__ gat_bias,
    u16* __restrict__ gat)
{
  extern __shared__ u16 lds[];
  u16* Ys = lds;                         // [256][136] u16 (overlay)

  const int tid = threadIdx.x;
  const int wave = tid >> 6, lane = tid & 63;
  const int wm = wave >> 1, wn = wave & 1;   // 4M x 2N, wave tile 64x64
  const int l15 = lane & 15, l4 = lane >> 4;

  const int raw = blockIdx.x;
  const int lin = (raw & 7) * 256 + (raw >> 3);
  const int img = lin >> 5;
  const int ntile = lin & 31;
  const int n0 = ntile * 128;
  const int jbg = ntile * 16;
  const size_t nbase = (size_t)img * NPIX;

  int offA[2], dstA[2];
#pragma unroll
  for (int i = 0; i < 2; ++i) {
    const int f = i * 512 + tid;
    const int r = f >> 2;
    const int kb = (f & 3) ^ ((r >> 1) & 3);
    offA[i] = r * 512 + kb * 8;
    dstA[i] = (i * 512 + wave * 64) * 8;
  }
  const int rB = tid >> 2;
  const int kbB = (tid & 3) ^ ((rB >> 1) & 3);
  const int offB = rB * 512 + kbB * 8;
  const int dstB = wave * 64 * 8;

  const u16* gA = A + (size_t)img * 256 * 512;
  const u16* gB = Btp + (size_t)n0 * 512;

  auto stage = [&](int t) {
    const int d = (t & 1) * 12288;
    gload_lds16(gA + t * 32 + offA[0], &lds[d + dstA[0]]);
    gload_lds16(gA + t * 32 + offA[1], &lds[d + dstA[1]]);
    gload_lds16(gB + t * 32 + offB, &lds[d + 8192 + dstB]);
  };

  f32x4 acc[4][4];
#pragma unroll
  for (int i = 0; i < 4; ++i)
#pragma unroll
    for (int j = 0; j < 4; ++j) acc[i][j] = f32x4{0.f, 0.f, 0.f, 0.f};

  const int kq = (l4 ^ ((l15 >> 1) & 3)) * 8;
  const int aBase = (wm * 64 + l15) * 32 + kq;
  const int bBase = 8192 + (wn * 64 + l15) * 32 + kq;

  stage(0);

  for (int t = 0; t < 16; ++t) {
    asm volatile("s_waitcnt vmcnt(0)" ::: "memory");
    __builtin_amdgcn_s_barrier();
    const int d = (t & 1) * 12288;
    bf16x8 af[4], bfr[4];
#pragma unroll
    for (int f = 0; f < 4; ++f) {
      af[f]  = *(const bf16x8*)&lds[d + aBase + f * 512];
      bfr[f] = *(const bf16x8*)&lds[d + bBase + f * 512];
    }
    if (t < 15) stage(t + 1);
    __builtin_amdgcn_s_setprio(1);
#pragma unroll
    for (int fm = 0; fm < 4; ++fm)
#pragma unroll
      for (int fn = 0; fn < 4; ++fn)
        acc[fm][fn] = __builtin_amdgcn_mfma_f32_16x16x32_bf16(
            bfr[fn], af[fm], acc[fm][fn], 0, 0, 0);
    __builtin_amdgcn_s_setprio(0);
  }
  __syncthreads();

#pragma unroll
  for (int fm = 0; fm < 4; ++fm) {
    const int nloc = wm * 64 + fm * 16 + l15;
#pragma unroll
    for (int fn = 0; fn < 4; ++fn) {
      const int cloc = wn * 64 + fn * 16 + l4 * 4;
      u16x4 ov;
#pragma unroll
      for (int r = 0; r < 4; ++r) ov[r] = f2b(acc[fm][fn][r]);
      *(u16x4*)&Ys[nloc * 136 + cloc] = ov;
    }
  }
  __syncthreads();

  const int n = tid >> 1, half = tid & 1;
  const int gi = n >> 4, gj = n & 15;
  int vv[5];
  vv[0] = n;
  vv[1] = (gi > 0)  ? n - 16 : n;
  vv[2] = (gi < 15) ? n + 16 : n;
  vv[3] = (gj > 0)  ? n - 1  : n;
  vv[4] = (gj < 15) ? n + 1  : n;
  U8u au[5];
  {
    const u16* ag = alf_g + (nbase + n) * 40;
#pragma unroll
    for (int e = 0; e < 5; ++e) au[e].v = *(const u16x8*)&ag[e * 8];
  }
  float o[8];
  {
    const int jb = jbg + half * 8;
    const float4 b0 = *(const float4*)&gat_bias[jb];
    const float4 b1 = *(const float4*)&gat_bias[jb + 4];
    o[0] = b0.x; o[1] = b0.y; o[2] = b0.z; o[3] = b0.w;
    o[4] = b1.x; o[5] = b1.y; o[6] = b1.z; o[7] = b1.w;
  }
#pragma unroll
  for (int e = 0; e < 5; ++e) {
    const u16* yrow = &Ys[vv[e] * 136 + half * 64];
#if defined(HAVE_DOT2)
#pragma unroll
    for (int k = 0; k < 8; ++k) {
      U8u yu;
      yu.v = *(const u16x8*)&yrow[k * 8];
      float s = o[k];
      s = __builtin_amdgcn_fdot2_f32_bf16(yu.p[0], au[e].p[0], s, false);
      s = __builtin_amdgcn_fdot2_f32_bf16(yu.p[1], au[e].p[1], s, false);
      s = __builtin_amdgcn_fdot2_f32_bf16(yu.p[2], au[e].p[2], s, false);
      s = __builtin_amdgcn_fdot2_f32_bf16(yu.p[3], au[e].p[3], s, false);
      o[k] = s;
    }
#else
    float a8[8];
#pragma unroll
    for (int h = 0; h < 8; ++h) a8[h] = b2f(au[e].v[h]);
#pragma unroll
    for (int k = 0; k < 8; ++k) {
      const u16x8 yv = *(const u16x8*)&yrow[k * 8];
#pragma unroll
      for (int h = 0; h < 8; ++h) o[k] += a8[h] * b2f(yv[h]);
    }
#endif
  }
  u16x8 ov;
#pragma unroll
  for (int k = 0; k < 8; ++k) ov[k] = f2b(o[k]);
  *(u16x8*)&gat[(nbase + n) * (size_t)CRED + jbg + half * 8] = ov;
}

// ===== 256x128 restore GEMM, 2-deep LDS (R19 recipe, R20-verified) =========
__global__ __launch_bounds__(512, 4) void gemm_res3_kernel(
    const u16* __restrict__ A, const u16* __restrict__ Bt,
    float* __restrict__ out32,
    const float* __restrict__ pg, const float* __restrict__ pb,
    const float* __restrict__ pm, const float* __restrict__ pv,
    const float* __restrict__ auxf)
{
  extern __shared__ u16 lds[];
  const int tid = threadIdx.x;
  const int wave = tid >> 6, lane = tid & 63;
  const int wm = wave >> 1, wn = wave & 1;
  const int l15 = lane & 15, l4 = lane >> 4;

  const int raw = blockIdx.x;
  const int lin = (raw & 7) * 64 + (raw >> 3);
  const int m0 = (lin >> 3) * 256;
  const int n0 = (lin & 7) * 128;

  int offA[2], dstA[2];
#pragma unroll
  for (int i = 0; i < 2; ++i) {
    const int f = i * 512 + tid;
    const int r = f >> 2;
    const int kb = (f & 3) ^ ((r >> 1) & 3);
    offA[i] = r * 512 + kb * 8;
    dstA[i] = (i * 512 + wave * 64) * 8;
  }
  const int rB = tid >> 2;
  const int kbB = (tid & 3) ^ ((rB >> 1) & 3);
  const int offB = rB * 512 + kbB * 8;
  const int dstB = wave * 64 * 8;

  const u16* gA = A + (size_t)m0 * 512;
  const u16* gB = Bt + (size_t)n0 * 512;

  auto stage = [&](int t) {
    const int d = (t & 1) * 12288;
    gload_lds16(gA + t * 32 + offA[0], &lds[d + dstA[0]]);
    gload_lds16(gA + t * 32 + offA[1], &lds[d + dstA[1]]);
    gload_lds16(gB + t * 32 + offB, &lds[d + 8192 + dstB]);
  };

  f32x4 acc[4][4];
#pragma unroll
  for (int i = 0; i < 4; ++i)
#pragma unroll
    for (int j = 0; j < 4; ++j) acc[i][j] = f32x4{0.f, 0.f, 0.f, 0.f};

  const int kq = (l4 ^ ((l15 >> 1) & 3)) * 8;
  const int aBase = (wm * 64 + l15) * 32 + kq;
  const int bBase = 8192 + (wn * 64 + l15) * 32 + kq;

  stage(0);

  for (int t = 0; t < 16; ++t) {
    asm volatile("s_waitcnt vmcnt(0)" ::: "memory");
    __builtin_amdgcn_s_barrier();
    const int d = (t & 1) * 12288;
    bf16x8 af[4], bfr[4];
#pragma unroll
    for (int f = 0; f < 4; ++f) {
      af[f]  = *(const bf16x8*)&lds[d + aBase + f * 512];
      bfr[f] = *(const bf16x8*)&lds[d + bBase + f * 512];
    }
    if (t < 15) stage(t + 1);
    __builtin_amdgcn_s_setprio(1);
#pragma unroll
    for (int fm = 0; fm < 4; ++fm)
#pragma unroll
      for (int fn = 0; fn < 4; ++fn)
        acc[fm][fn] = __builtin_amdgcn_mfma_f32_16x16x32_bf16(
            af[fm], bfr[fn], acc[fm][fn], 0, 0, 0);
    __builtin_amdgcn_s_setprio(0);
  }

  const int rowb = m0 + wm * 64 + l4 * 4;
#pragma unroll
  for (int fn = 0; fn < 4; ++fn) {
    const int col = n0 + wn * 64 + fn * 16 + l15;
    const float sc = pg[col] * rsqrtf(pv[col] + EPSB);
    const float off = pb[col] - pm[col] * sc;
#pragma unroll
    for (int fm = 0; fm < 4; ++fm) {
      const int row = rowb + fm * 16;
      const int bimg = row >> 8, p0 = row & 255;
      const size_t oa = (size_t)bimg * (COUT * NPIX) + (size_t)col * NPIX + p0;
      const float4 rv = *(const float4*)&auxf[oa];
      float4 ov;
      ov.x = fmaxf(acc[fm][fn][0] * sc + off + rv.x, 0.f);
      ov.y = fmaxf(acc[fm][fn][1] * sc + off + rv.y, 0.f);
      ov.z = fmaxf(acc[fm][fn][2] * sc + off + rv.z, 0.f);
      ov.w = fmaxf(acc[fm][fn][3] * sc + off + rv.w, 0.f);
      *(float4*)&out32[oa] = ov;
    }
  }
}

// ===== WgT2p[j*8+h][k] = bf16(w_gat[k][h*512+j])  (column reorder) =========
__global__ __launch_bounds__(256) void wgatp_kernel(
    const float* __restrict__ w_gat, u16* __restrict__ out)
{
  __shared__ float tile[64][65];
  const int cb = blockIdx.x;
  const int kb = blockIdx.y;
  const int t = threadIdx.x;
  const int jl = t & 7, h = (t >> 3) & 7, k4 = t >> 6;
#pragma unroll
  for (int i = 0; i < 16; ++i) {
    const int kl = k4 * 16 + i;
    tile[kl][jl * 8 + h] =
        w_gat[(size_t)(kb * 64 + kl) * KGAT + h * 512 + cb * 8 + jl];
  }
  __syncthreads();
#pragma unroll
  for (int i = 0; i < 4; ++i) {
    const int idx = i * 256 + t;
    const int cl = idx >> 4;
    const int kq = (idx & 15) * 4;
    u16x4 ov;
#pragma unroll
    for (int q = 0; q < 4; ++q) ov[q] = f2b(tile[kq + q][cl]);
    *(u16x4*)&out[(size_t)(cb * 64 + cl) * CRED + kb * 64 + kq] = ov;
  }
}

// ====== 64x128 FUSED reduce GEMM, DOUBLE-BUFFERED (one barrier/K-tile) =====
// xr = relu(bn(x_nchw @ w_reduce^T)).  A packed from NCHW fp32 in regs ->
// swizzled ds_write into buf (t+1)&1 while computing buf t&1; B via
// gload_lds into the same alternate buffer.  __syncthreads (drains vm+lgkm)
// publishes buf t at top of iteration t.  4 blocks/CU (24KB LDS, ~90 VGPR).
__global__ __launch_bounds__(256, 4) void gemm_redf_kernel(
    const float* __restrict__ x, const u16* __restrict__ Bt,
    u16* __restrict__ out16,
    const float* __restrict__ pg, const float* __restrict__ pb,
    const float* __restrict__ pm, const float* __restrict__ pv)
{
  __shared__ u16 As[2][64 * 32];
  __shared__ u16 Bs[2][128 * 32];
  const int tid = threadIdx.x;
  const int wave = tid >> 6, lane = tid & 63;
  const int gx = gridDim.x;
  const int nwg = gx * gridDim.y;
  int lin = blockIdx.y * gx + blockIdx.x;
  lin = (lin & 7) * (nwg >> 3) + (lin >> 3);
  const int m0 = (lin / gx) * 64, n0 = (lin % gx) * 128;
  const int bimg = m0 >> 8, p0 = m0 & 255;

  const float* xsrc = x + (size_t)bimg * CIN * NPIX + p0 + lane;

  int offB[2], dstB[2];
#pragma unroll
  for (int i = 0; i < 2; ++i) {
    const int f = i * 256 + tid;
    const int r = f >> 2;
    const int kb = (f & 3) ^ ((r >> 1) & 3);
    offB[i] = r * CIN + kb * 8;
    dstB[i] = (i * 256 + wave * 64) * 8;
  }
  const u16* gB = Bt + (size_t)n0 * CIN;

  const int aWr = (lane * 4 + (wave ^ ((lane >> 1) & 3))) * 8;

  f32x4 acc[2][4];
#pragma unroll
  for (int i = 0; i < 2; ++i)
#pragma unroll
    for (int j = 0; j < 4; ++j) acc[i][j] = f32x4{0.f, 0.f, 0.f, 0.f};

  const int wr = wave >> 1, wc = wave & 1;
  const int l15 = lane & 15, l4 = lane >> 4;
  const int kq = (l4 ^ ((l15 >> 1) & 3)) * 8;

  // prologue: tile 0 -> buf 0
  float av[8];
#pragma unroll
  for (int j = 0; j < 8; ++j) av[j] = xsrc[(wave * 8 + j) * NPIX];
  {
    u16x8 pvv;
#pragma unroll
    for (int j = 0; j < 8; ++j) pvv[j] = f2b(av[j]);
    *(u16x8*)&As[0][aWr] = pvv;
  }
  gload_lds16(gB + offB[0], &Bs[0][dstB[0]]);
  gload_lds16(gB + offB[1], &Bs[0][dstB[1]]);

  for (int t = 0; t < 32; ++t) {
    __syncthreads();                 // buf t&1 resident (vm+lgkm drained)
    const int cur = t & 1, nxt = cur ^ 1;
    const int ktn = (t + 1) * 32;
    if (t < 31) {
#pragma unroll
      for (int j = 0; j < 8; ++j)
        av[j] = xsrc[(ktn + wave * 8 + j) * NPIX];
      gload_lds16(gB + ktn + offB[0], &Bs[nxt][dstB[0]]);
      gload_lds16(gB + ktn + offB[1], &Bs[nxt][dstB[1]]);
    }
    bf16x8 af[2], bfr[4];
#pragma unroll
    for (int f = 0; f < 2; ++f)
      af[f] = *(const bf16x8*)&As[cur][(wr * 32 + f * 16 + l15) * 32 + kq];
#pragma unroll
    for (int f = 0; f < 4; ++f)
      bfr[f] = *(const bf16x8*)&Bs[cur][(wc * 64 + f * 16 + l15) * 32 + kq];
    __builtin_amdgcn_s_setprio(1);
#pragma unroll
    for (int fm = 0; fm < 2; ++fm)
#pragma unroll
      for (int fn = 0; fn < 4; ++fn)
        acc[fm][fn] = __builtin_amdgcn_mfma_f32_16x16x32_bf16(
            af[fm], bfr[fn], acc[fm][fn], 0, 0, 0);
    __builtin_amdgcn_s_setprio(0);
    if (t < 31) {
      u16x8 pvv;
#pragma unroll
      for (int j = 0; j < 8; ++j) pvv[j] = f2b(av[j]);
      *(u16x8*)&As[nxt][aWr] = pvv;   // different buffer than readers
    }
  }

  const int rowb = m0 + wr * 32 + (lane >> 4) * 4;
#pragma unroll
  for (int fn = 0; fn < 4; ++fn) {
    const int col = n0 + wc * 64 + fn * 16 + l15;
    const float sc = pg[col] * rsqrtf(pv[col] + EPSB);
    const float off = pb[col] - pm[col] * sc;
#pragma unroll
    for (int fm = 0; fm < 2; ++fm) {
      const int row = rowb + fm * 16;
#pragma unroll
      for (int r = 0; r < 4; ++r) {
        const float y = fmaxf(acc[fm][fn][r] * sc + off, 0.f);
        out16[(size_t)(row + r) * CRED + col] = f2b(y);
      }
    }
  }
}

// --------- elementwise fp32 -> bf16 convert, two buffers, one launch -------
__global__ __launch_bounds__(256) void cvt2_kernel(
    const float* __restrict__ s0, u16* __restrict__ d0,
    const float* __restrict__ s1, u16* __restrict__ d1, int half)
{
  const int bi = blockIdx.x;
  const float* src = (bi < half) ? s0 : s1;
  u16* dst = (bi < half) ? d0 : d1;
  const int i = ((bi < half ? bi : bi - half) * 256 + threadIdx.x) * 8;
  const float4 a = *(const float4*)&src[i];
  const float4 b = *(const float4*)&src[i + 4];
  u16x8 o;
  o[0] = f2b(a.x); o[1] = f2b(a.y); o[2] = f2b(a.z); o[3] = f2b(a.w);
  o[4] = f2b(b.x); o[5] = f2b(b.y); o[6] = f2b(b.z); o[7] = f2b(b.w);
  *(u16x8*)&dst[i] = o;
}

// ---------- P[s][h][c] = sum_t w_gat[c][h*512+t] * att_s[h][t] -------------
__global__ __launch_bounds__(128) void attproj_kernel(
    const float* __restrict__ w_gat, const float* __restrict__ att_src,
    const float* __restrict__ att_dst, float* __restrict__ P)
{
  __shared__ float av[CRED];
  const int bi = blockIdx.x;
  const int sh = bi & 15, q = bi >> 4;
  const int s = sh >> 3, h = sh & 7;
  const float* att = (s == 0) ? att_src : att_dst;
  for (int t = threadIdx.x; t < CRED; t += 128) av[t] = att[h * CRED + t];
  __syncthreads();
  const int c = q * 128 + threadIdx.x;
  const float* wrow = w_gat + (size_t)c * KGAT + h * CRED;
  float acc = 0.f;
  for (int j = 0; j < CRED; j += 4) {
    const float4 w = *(const float4*)&wrow[j];
    acc += w.x * av[j] + w.y * av[j + 1] + w.z * av[j + 2] + w.w * av[j + 3];
  }
  P[(size_t)sh * CRED + c] = acc;
}

// ---------- a_all[s][n][h] = xr[n] . P[s][h]   (one wave per node) ---------
__global__ __launch_bounds__(256) void att_kernel(
    const u16* __restrict__ xr, const float* __restrict__ P,
    float* __restrict__ a_all)
{
  const int wave = threadIdx.x >> 6, lane = threadIdx.x & 63;
  const int m = blockIdx.x * 4 + wave;
  const int sh = lane & 15, q = lane >> 4;
  const u16* xp = xr + (size_t)m * CRED + q * 128;
  const float* Pp = P + (size_t)sh * CRED + q * 128;
  float s = 0.f;
#pragma unroll
  for (int c = 0; c < 128; c += 8) {
    u16x8 xv = *(const u16x8*)&xp[c];
#pragma unroll
    for (int t = 0; t < 8; ++t) s += b2f(xv[t]) * Pp[c + t];
  }
  s += __shfl_xor(s, 16);
  s += __shfl_xor(s, 32);
  if (q == 0)
    a_all[(size_t)(sh >> 3) * MTOT * HEADS + (size_t)m * HEADS + (sh & 7)] = s;
}

// ---------------------------------------------------------------------------
extern "C" void kernel_launch(void* const* d_in, const int* in_sizes, int n_in,
                              void* d_out, int out_size, void* d_ws, size_t ws_size,
                              hipStream_t stream)
{
  const float* x         = (const float*)d_in[0];
  const float* w_reduce  = (const float*)d_in[1];
  const float* g_red     = (const float*)d_in[2];
  const float* b_red     = (const float*)d_in[3];
  const float* m_red     = (const float*)d_in[4];
  const float* v_red     = (const float*)d_in[5];
  const float* w_gat     = (const float*)d_in[6];
  const float* att_src   = (const float*)d_in[7];
  const float* att_dst   = (const float*)d_in[8];
  const float* gat_bias  = (const float*)d_in[9];
  const float* w_restore = (const float*)d_in[10];
  const float* g_res     = (const float*)d_in[11];
  const float* b_res     = (const float*)d_in[12];
  const float* m_res     = (const float*)d_in[13];
  const float* v_res     = (const float*)d_in[14];

  constexpr size_t SZ_XR   = (size_t)MTOT * CRED * 2;
  constexpr size_t SZ_GAT  = SZ_XR;
  constexpr size_t SZ_WGT  = (size_t)KGAT * CRED * 2;
  constexpr size_t SZ_WRD  = (size_t)CRED * CIN * 2;
  constexpr size_t SZ_WRS  = (size_t)COUT * CRED * 2;
  constexpr size_t SZ_P    = (size_t)16 * CRED * 4;
  constexpr size_t SZ_AALL = (size_t)2 * MTOT * HEADS * 4;
  char* ws = (char*)d_ws;
  u16*   xr     = (u16*)ws;
  u16*   gat    = (u16*)(ws + SZ_XR);
  u16*   WgT2p  = (u16*)(ws + SZ_XR + SZ_GAT);
  u16*   wred_b = (u16*)(ws + SZ_XR + SZ_GAT + SZ_WGT);
  u16*   wres_b = (u16*)(ws + SZ_XR + SZ_GAT + SZ_WGT + SZ_WRD);
  float* P      = (float*)(ws + SZ_XR + SZ_GAT + SZ_WGT + SZ_WRD + SZ_WRS);
  float* a_all  = (float*)(ws + SZ_XR + SZ_GAT + SZ_WGT + SZ_WRD + SZ_WRS + SZ_P);
  u16*   alf_g  = (u16*)(ws + SZ_XR + SZ_GAT + SZ_WGT + SZ_WRD + SZ_WRS + SZ_P + SZ_AALL);
  float* outp   = (float*)d_out;

  hipFuncSetAttribute((const void*)gemmf2_kernel,
                      hipFuncAttributeMaxDynamicSharedMemorySize, 69632);
  hipFuncSetAttribute((const void*)gemm_res3_kernel,
                      hipFuncAttributeMaxDynamicSharedMemorySize, 49152);

  wgatp_kernel<<<dim3(64, 8), 256, 0, stream>>>(w_gat, WgT2p);
  cvt2_kernel<<<512, 256, 0, stream>>>(
      w_reduce, wred_b, w_restore, wres_b, 256);
  gemm_redf_kernel<<<dim3(4, 256), 256, 0, stream>>>(
      x, wred_b, xr, g_red, b_red, m_red, v_red);
  attproj_kernel<<<64, 128, 0, stream>>>(w_gat, att_src, att_dst, P);
  att_kernel<<<MTOT / 4, 256, 0, stream>>>(xr, P, a_all);
  alphapre_kernel<<<512, 256, 0, stream>>>(a_all, alf_g);
  gemmf2_kernel<<<2048, 512, 69632, stream>>>(
      xr, WgT2p, alf_g, gat_bias, gat);
  gemm_res3_kernel<<<512, 512, 49152, stream>>>(
      gat, wres_b, outp, g_res, b_res, m_res, v_res, x);
  (void)in_sizes; (void)n_in; (void)out_size; (void)ws_size;
}